// Round 4
// baseline (1313.351 us; speedup 1.0000x reference)
//
#include <hip/hip_runtime.h>
#include <hip/hip_bf16.h>
#include <math.h>

// Problem constants
#define BATCH 32
#define IN_LEN 28
#define NN 2048
#define E 256
#define H 512
#define N_LAYERS 3
#define OUT_LEN 28
#define M_ROWS (BATCH * NN)   // 65536

typedef unsigned short u16;
typedef unsigned int   u32;
typedef __attribute__((ext_vector_type(8))) short short8;   // 8 bf16 (4 VGPRs)
typedef __attribute__((ext_vector_type(4))) float f32x4;    // MFMA accumulator

// ---- bf16 split helpers (RNE) ----------------------------------------------
__device__ __forceinline__ u16 f2bf(float x) {
    union { float f; u32 u; } v; v.f = x;
    u32 r = (v.u + 0x7FFFu + ((v.u >> 16) & 1u)) >> 16;
    return (u16)r;
}
__device__ __forceinline__ float bf2f(u16 h) {
    union { u32 u; float f; } v; v.u = ((u32)h) << 16;
    return v.f;
}

// async global -> LDS, 16 B per lane. LDS dest = wave-uniform base + lane*16.
__device__ __forceinline__ void gload_lds16(const void* g, void* l) {
    __builtin_amdgcn_global_load_lds(
        (const __attribute__((address_space(1))) void*)g,
        (__attribute__((address_space(3))) void*)l, 16, 0, 0);
}

// ---------------------------------------------------------------------------
// Split an fp32 array into bf16 hi/lo arrays.
// ---------------------------------------------------------------------------
__global__ __launch_bounds__(256)
void k_split(const float* __restrict__ src, u16* __restrict__ hi,
             u16* __restrict__ lo, int n)
{
    int i = blockIdx.x * 256 + threadIdx.x;
    if (i < n) {
        float v = src[i];
        u16 h = f2bf(v);
        hi[i] = h;
        lo[i] = f2bf(v - bf2f(h));
    }
}

// ---------------------------------------------------------------------------
// Kernel 1: ts = flat @ W_ts^T + b_ts ; h = concat([ts, node_emb]) -> split
// ---------------------------------------------------------------------------
__global__ __launch_bounds__(256)
void k_ts(const float* __restrict__ x_node, const float* __restrict__ node_emb,
          const float* __restrict__ W_ts, const float* __restrict__ b_ts,
          u16* __restrict__ hhi, u16* __restrict__ hlo)
{
    __shared__ float xs[IN_LEN][64];
    const int tid = threadIdx.x;
    const int b   = blockIdx.y;
    const int n0  = blockIdx.x * 64;

    for (int idx = tid; idx < IN_LEN * 64; idx += 256) {
        int l = idx >> 6, i = idx & 63;
        xs[l][i] = x_node[((size_t)b * IN_LEN + l) * NN + n0 + i];
    }
    __syncthreads();

    float w[IN_LEN];
    #pragma unroll
    for (int j = 0; j < IN_LEN; j++) w[j] = W_ts[tid * IN_LEN + j];
    const float bias = b_ts[tid];

    for (int i = 0; i < 64; i++) {
        float acc = bias;
        #pragma unroll
        for (int j = 0; j < IN_LEN; j++) acc += xs[j][i] * w[j];
        size_t row = (size_t)b * NN + n0 + i;
        u16 thi = f2bf(acc);
        hhi[row * H + tid] = thi;
        hlo[row * H + tid] = f2bf(acc - bf2f(thi));
        float ev = node_emb[(size_t)(n0 + i) * 256 + tid];
        u16 ehi = f2bf(ev);
        hhi[row * H + E + tid] = ehi;
        hlo[row * H + E + tid] = f2bf(ev - bf2f(ehi));
    }
}

// ---------------------------------------------------------------------------
// Kernel 2: MFMA GEMM, split-bf16, FULL-N tile with double-buffered pipeline.
//   C[r,o] = sum_k A[r,k]*W[o,k]  via  Ahi*Whi + Ahi*Wlo + Alo*Whi
// Tile 64 rows x 512 cols; 512 thr = 8 waves, wave wv -> cols 64*wv..64*wv+63,
// each wave 4x4 of 16x16x32 MFMA. BK=32, 16 K-steps.
// LDS (dynamic, 144 KB): A-tiles (hi/lo) and W-tiles (hi/lo) double-buffered.
// One barrier per K-step; stage(t+1) issues before compute(t) so the
// vmcnt(0)-before-barrier drain lands after the MFMA burst.
// A is fetched exactly once from HBM (no col-block re-read); W streams from L2.
// XOR chunk swizzle on the global source side keeps fragment reads 2-way free.
// grid (M/64); block 512.
// MODE 0: out = relu(acc+bias) -> split; MODE 1: out = acc+bias+res -> split.
// ---------------------------------------------------------------------------
template <int MODE>
__global__ __launch_bounds__(512, 2)
void k_gemm(const u16* __restrict__ Ahi, const u16* __restrict__ Alo,
            const u16* __restrict__ Whi, const u16* __restrict__ Wlo,
            const float* __restrict__ bias,
            const u16* ResHi, const u16* ResLo,
            u16* OutHi, u16* OutLo)
{
    extern __shared__ __align__(16) u16 smem[];
    u16* sAhi = smem;                  // [2][64*32]   = 2*2048
    u16* sAlo = sAhi + 2 * 2048;       // [2][64*32]
    u16* sWhi = sAlo + 2 * 2048;       // [2][512*32]  = 2*16384
    u16* sWlo = sWhi + 2 * 16384;      // [2][512*32]

    const int tid  = threadIdx.x;
    const int ln   = tid & 63;
    const int wv   = tid >> 6;         // 0..7
    const int row0 = blockIdx.x * 64;
    const int cw   = wv * 64;          // wave's col base

    const int lr = ln >> 2;            // lane row within a 16-row issue chunk
    const int lc = ln & 3;             // lane 8-elem chunk within row

    // stage K-slice kt into buffer p: 72 x 1KB issues, 9 per wave.
    // q in [0,4): Ahi ; [4,8): Alo ; [8,40): Whi ; [40,72): Wlo
    auto stage = [&](int p, int kt) {
        #pragma unroll
        for (int j = 0; j < 9; j++) {
            int q = wv * 9 + j;                      // wave-uniform
            const u16* src; u16* dst; int grow0;
            if (q < 4)       { src = Ahi; dst = sAhi + p * 2048  + q * 512;        grow0 = row0 + q * 16; }
            else if (q < 8)  { src = Alo; dst = sAlo + p * 2048  + (q - 4) * 512;  grow0 = row0 + (q - 4) * 16; }
            else if (q < 40) { src = Whi; dst = sWhi + p * 16384 + (q - 8) * 512;  grow0 = (q - 8) * 16; }
            else             { src = Wlo; dst = sWlo + p * 16384 + (q - 40) * 512; grow0 = (q - 40) * 16; }
            int grow = grow0 + lr;
            int sc   = lc ^ ((grow >> 1) & 3);       // swizzled source chunk
            gload_lds16(src + (size_t)grow * H + kt + sc * 8, dst);
        }
    };

    f32x4 acc[4][4];
    #pragma unroll
    for (int m = 0; m < 4; m++)
        #pragma unroll
        for (int n = 0; n < 4; n++) acc[m][n] = (f32x4)(0.f);

    stage(0, 0);

    for (int t = 0; t < 16; t++) {
        const int p = t & 1;
        __syncthreads();                    // buf p drained; buf 1-p free to write
        if (t + 1 < 16) stage(1 - p, (t + 1) * 32);   // prefetch flies over MFMA burst

        short8 ahi[4], alo[4], whi[4], wlo[4];
        #pragma unroll
        for (int m = 0; m < 4; m++) {
            int rr = m * 16 + (ln & 15);
            int c  = ((ln >> 4) ^ ((rr >> 1) & 3)) * 8;
            ahi[m] = *(const short8*)&sAhi[p * 2048 + rr * 32 + c];
            alo[m] = *(const short8*)&sAlo[p * 2048 + rr * 32 + c];
        }
        #pragma unroll
        for (int n = 0; n < 4; n++) {
            int wr = cw + n * 16 + (ln & 15);
            int c  = ((ln >> 4) ^ ((wr >> 1) & 3)) * 8;
            whi[n] = *(const short8*)&sWhi[p * 16384 + wr * 32 + c];
            wlo[n] = *(const short8*)&sWlo[p * 16384 + wr * 32 + c];
        }
        #pragma unroll
        for (int m = 0; m < 4; m++)
            #pragma unroll
            for (int n = 0; n < 4; n++) {
                acc[m][n] = __builtin_amdgcn_mfma_f32_16x16x32_bf16(ahi[m], whi[n], acc[m][n], 0, 0, 0);
                acc[m][n] = __builtin_amdgcn_mfma_f32_16x16x32_bf16(ahi[m], wlo[n], acc[m][n], 0, 0, 0);
                acc[m][n] = __builtin_amdgcn_mfma_f32_16x16x32_bf16(alo[m], whi[n], acc[m][n], 0, 0, 0);
            }
    }

    // epilogue: C/D layout col=lane&15, row=(lane>>4)*4+reg
    #pragma unroll
    for (int m = 0; m < 4; m++) {
        #pragma unroll
        for (int r = 0; r < 4; r++) {
            int grow = row0 + m * 16 + (ln >> 4) * 4 + r;
            #pragma unroll
            for (int n = 0; n < 4; n++) {
                int gcol = cw + n * 16 + (ln & 15);
                float v = acc[m][n][r] + bias[gcol];
                size_t idx = (size_t)grow * H + gcol;
                if (MODE == 0) {
                    v = fmaxf(v, 0.f);
                } else {
                    v += bf2f(ResHi[idx]) + bf2f(ResLo[idx]);
                }
                u16 hi = f2bf(v);
                OutHi[idx] = hi;
                OutLo[idx] = f2bf(v - bf2f(hi));
            }
        }
    }
}

// ---------------------------------------------------------------------------
// Kernel 3: b = sigmoid(h @ Wb^T), g = sigmoid(h @ Wg^T); h from hi+lo
// ---------------------------------------------------------------------------
__global__ __launch_bounds__(256)
void k_head(const u16* __restrict__ hhi, const u16* __restrict__ hlo,
            const float* __restrict__ Wb, const float* __restrict__ bb,
            const float* __restrict__ Wg, const float* __restrict__ bg,
            float* __restrict__ bArr, float* __restrict__ gArr)
{
    const int lane = threadIdx.x & 63;
    const int row  = blockIdx.x * 4 + (threadIdx.x >> 6);

    uint4 uh = *(const uint4*)(hhi + (size_t)row * H + lane * 8);
    uint4 ul = *(const uint4*)(hlo + (size_t)row * H + lane * 8);
    u32 ph[4] = {uh.x, uh.y, uh.z, uh.w};
    u32 pl[4] = {ul.x, ul.y, ul.z, ul.w};
    float hv[8];
    #pragma unroll
    for (int k = 0; k < 4; k++) {
        hv[2 * k]     = bf2f((u16)(ph[k] & 0xFFFF)) + bf2f((u16)(pl[k] & 0xFFFF));
        hv[2 * k + 1] = bf2f((u16)(ph[k] >> 16))    + bf2f((u16)(pl[k] >> 16));
    }
    float4 wb0 = *(const float4*)(Wb + lane * 8);
    float4 wb1 = *(const float4*)(Wb + lane * 8 + 4);
    float4 wg0 = *(const float4*)(Wg + lane * 8);
    float4 wg1 = *(const float4*)(Wg + lane * 8 + 4);

    float sb = hv[0] * wb0.x + hv[1] * wb0.y + hv[2] * wb0.z + hv[3] * wb0.w
             + hv[4] * wb1.x + hv[5] * wb1.y + hv[6] * wb1.z + hv[7] * wb1.w;
    float sg = hv[0] * wg0.x + hv[1] * wg0.y + hv[2] * wg0.z + hv[3] * wg0.w
             + hv[4] * wg1.x + hv[5] * wg1.y + hv[6] * wg1.z + hv[7] * wg1.w;

    #pragma unroll
    for (int off = 32; off >= 1; off >>= 1) {
        sb += __shfl_xor(sb, off);
        sg += __shfl_xor(sg, off);
    }
    if (lane == 0) {
        bArr[row] = 1.f / (1.f + expf(-(sb + bb[0])));
        gArr[row] = 1.f / (1.f + expf(-(sg + bg[0])));
    }
}

// ---------------------------------------------------------------------------
// Kernel 4: per-(b,n) SIR recurrence. thread per row.
// ---------------------------------------------------------------------------
__global__ __launch_bounds__(256)
void k_sir(const float* __restrict__ x_state,
           const float* __restrict__ bArr, const float* __restrict__ gArr,
           float* __restrict__ out)
{
    const int row = blockIdx.x * 256 + threadIdx.x;   // b*NN + n
    const int bb_ = row / NN;
    const int n   = row % NN;

    const float g = gArr[row];
    const float b = bArr[row];
    const float d = expf(-g);

    const float* xs = x_state + ((size_t)bb_ * IN_LEN) * (NN * 3) + (size_t)n * 3;

    float x1_prev = xs[1];
    float Ih_prev = x1_prev / g;
    float acc = 0.f;
    #pragma unroll 4
    for (int t = 1; t <= IN_LEN - 1; ++t) {
        float x1 = xs[(size_t)t * (NN * 3) + 1];
        float Ih = x1 / g;
        float Iin = fmaxf(Ih - Ih_prev + x1_prev, 0.f);
        acc = acc * d + Iin;
        Ih_prev = Ih;
        x1_prev = x1;
    }
    float ITm1 = acc * d;
    float Npop = xs[(size_t)(IN_LEN - 1) * (NN * 3) + 2];
    float RTm1 = Npop - xs[(size_t)(IN_LEN - 2) * (NN * 3) + 0];
    float STm1 = Npop - ITm1 - RTm1;
    float Iin0 = b * STm1 * ITm1 / Npop;
    float S = STm1 - Iin0;
    float I = d * (ITm1 + Iin0);

    float* op = out + ((size_t)bb_ * OUT_LEN) * NN + n;
    #pragma unroll 4
    for (int k = 0; k < OUT_LEN; k++) {
        float Iin = b * S * I / Npop;
        S = S - Iin;
        float Rin = g * I;
        I = d * (I + Iin);
        op[(size_t)k * NN] = Rin;
    }
}

// ---------------------------------------------------------------------------
extern "C" void kernel_launch(void* const* d_in, const int* in_sizes, int n_in,
                              void* d_out, int out_size, void* d_ws, size_t ws_size,
                              hipStream_t stream)
{
    const float* x_node   = (const float*)d_in[0];
    const float* x_state  = (const float*)d_in[1];
    const float* node_emb = (const float*)d_in[2];
    const float* W_ts     = (const float*)d_in[3];
    const float* b_ts     = (const float*)d_in[4];
    const float* enc_W1   = (const float*)d_in[5];
    const float* enc_b1   = (const float*)d_in[6];
    const float* enc_W2   = (const float*)d_in[7];
    const float* enc_b2   = (const float*)d_in[8];
    const float* Wb       = (const float*)d_in[9];
    const float* bb       = (const float*)d_in[10];
    const float* Wg       = (const float*)d_in[11];
    const float* bg       = (const float*)d_in[12];
    float* out = (float*)d_out;

    // allow 144 KB dynamic LDS on the GEMM kernels (gfx950 LDS/WG = 160 KB)
    const int LDS_BYTES = 147456;
    static bool attrDone = false;
    if (!attrDone) {
        hipFuncSetAttribute((const void*)k_gemm<0>,
                            hipFuncAttributeMaxDynamicSharedMemorySize, LDS_BYTES);
        hipFuncSetAttribute((const void*)k_gemm<1>,
                            hipFuncAttributeMaxDynamicSharedMemorySize, LDS_BYTES);
        attrDone = true;
    }

    // Workspace: hhi 64M | hlo 64M | wHi 3M | wLo 3M | bArr | gArr | z (chunked)
    u16* hhi   = (u16*)d_ws;
    u16* hlo   = hhi + (size_t)M_ROWS * H;
    u16* wHi   = hlo + (size_t)M_ROWS * H;          // [6][512][512]
    u16* wLo   = wHi + (size_t)6 * H * H;
    float* bArr = (float*)(wLo + (size_t)6 * H * H);
    float* gArr = bArr + M_ROWS;
    u16* zhi   = (u16*)(gArr + M_ROWS);

    size_t used  = (size_t)((char*)zhi - (char*)d_ws);
    size_t avail = (ws_size > used) ? ws_size - used : 0;
    long long chunkLL = (long long)(avail / (H * 2 * sizeof(u16))) & ~127LL;
    int chunk = (chunkLL > M_ROWS) ? M_ROWS : (int)chunkLL;
    if (chunk < 128) chunk = 128;
    u16* zlo = zhi + (size_t)chunk * H;

    // weight conversion (redone every call; d_ws is re-poisoned)
    const int nW = N_LAYERS * H * H;   // 786432
    k_split<<<nW / 256, 256, 0, stream>>>(enc_W1, wHi, wLo, nW);
    k_split<<<nW / 256, 256, 0, stream>>>(enc_W2, wHi + nW, wLo + nW, nW);

    // 1. build h (split)
    k_ts<<<dim3(NN / 64, BATCH), 256, 0, stream>>>(x_node, node_emb, W_ts, b_ts, hhi, hlo);

    // 2. encoder layers (row-chunked so z fits in workspace)
    for (int l = 0; l < N_LAYERS; l++) {
        const u16* W1hi = wHi + (size_t)l * H * H;
        const u16* W1lo = wLo + (size_t)l * H * H;
        const u16* W2hi = wHi + (size_t)nW + (size_t)l * H * H;
        const u16* W2lo = wLo + (size_t)nW + (size_t)l * H * H;
        const float* b1 = enc_b1 + (size_t)l * H;
        const float* b2 = enc_b2 + (size_t)l * H;
        for (int r = 0; r < M_ROWS; r += chunk) {
            int rows = (M_ROWS - r < chunk) ? (M_ROWS - r) : chunk;
            u16* hrhi = hhi + (size_t)r * H;
            u16* hrlo = hlo + (size_t)r * H;
            k_gemm<0><<<rows / 64, 512, LDS_BYTES, stream>>>(
                hrhi, hrlo, W1hi, W1lo, b1, nullptr, nullptr, zhi, zlo);
            k_gemm<1><<<rows / 64, 512, LDS_BYTES, stream>>>(
                zhi, zlo, W2hi, W2lo, b2, hrhi, hrlo, hrhi, hrlo);
        }
    }

    // 3. heads
    k_head<<<M_ROWS / 4, 256, 0, stream>>>(hhi, hlo, Wb, bb, Wg, bg, bArr, gArr);

    // 4. SIR recurrence + output
    k_sir<<<M_ROWS / 256, 256, 0, stream>>>(x_state, bArr, gArr, out);
}